// Round 1
// baseline (700.983 us; speedup 1.0000x reference)
//
#include <hip/hip_runtime.h>
#include <stdint.h>

// ---------------- common helpers ----------------

using f32x4 = __attribute__((ext_vector_type(4))) float;
using s16x8 = __attribute__((ext_vector_type(8))) short;

__device__ __forceinline__ ushort f2b(float f) {
    union { float f; uint32_t u; } v; v.f = f;
    uint32_t u = v.u;
    return (ushort)((u + 0x7fffu + ((u >> 16) & 1u)) >> 16);
}
__device__ __forceinline__ float b2f(ushort b) {
    union { uint32_t u; float f; } v; v.u = ((uint32_t)b) << 16;
    return v.f;
}
__device__ __forceinline__ float to_f(float f) { return f; }
__device__ __forceinline__ float to_f(ushort b) { return b2f(b); }

// ---------------- cast fp32 -> bf16 (vectorized x4) ----------------

__global__ __launch_bounds__(256) void cast_f2b4(const float* __restrict__ src,
                                                 ushort* __restrict__ dst,
                                                 long long n4) {
    long long i = (long long)blockIdx.x * 256 + threadIdx.x;
    if (i >= n4) return;
    float4 f = ((const float4*)src)[i];
    ushort4 o;
    o.x = f2b(f.x); o.y = f2b(f.y); o.z = f2b(f.z); o.w = f2b(f.w);
    ((ushort4*)dst)[i] = o;
}

// ---------------- transpose (fp32 or bf16 in) -> bf16 out ----------------
// src: [R][C] row-major, dst: [C][R] row-major. Grid: (C/32, R/32, batch), block (32,8).

template <typename T>
__global__ __launch_bounds__(256) void transpose_to_bf16(const T* __restrict__ src,
                                                         ushort* __restrict__ dst,
                                                         int R, int C,
                                                         long long ss, long long ds) {
    __shared__ float tile[32][33];
    src += (long long)blockIdx.z * ss;
    dst += (long long)blockIdx.z * ds;
    const int c0 = blockIdx.x * 32;
    const int r0 = blockIdx.y * 32;
    const int tx = threadIdx.x, ty = threadIdx.y;
#pragma unroll
    for (int i = 0; i < 4; i++) {
        int r = r0 + ty + i * 8;
        tile[ty + i * 8][tx] = to_f(src[(long long)r * C + c0 + tx]);
    }
    __syncthreads();
#pragma unroll
    for (int i = 0; i < 4; i++) {
        int r = c0 + ty + i * 8;  // row of dst, in [0, C)
        dst[(long long)r * R + r0 + tx] = f2b(tile[tx][ty + i * 8]);
    }
}

// ---------------- bf16 MFMA GEMM:  C[M,N] = A[M,K] * BT[N,K]^T (+bias, relu, scale) ----
// 128x128 tile per 256-thread block (4 waves, each 64x64 = 4x4 MFMA 16x16x32 tiles).
// Grid: (N/128, M/128, batch). All dims must divide exactly (true for all uses here).

#define BM 128
#define BN 128
#define BKK 32
#define LDSP (BKK + 8)  // padded row: 40 elems = 80 B -> breaks pow2 bank stride

template <int OUT_BF16, int RELU, int HAS_BIAS>
__global__ __launch_bounds__(256) void gemm_bt(const ushort* __restrict__ A,
                                               const ushort* __restrict__ BT,
                                               void* __restrict__ Cp,
                                               const float* __restrict__ bias,
                                               int M, int N, int K, float scale,
                                               long long sA, long long sB, long long sC) {
    __shared__ ushort As[BM * LDSP];
    __shared__ ushort Bs[BN * LDSP];

    const int tid = threadIdx.x;
    const int bz = blockIdx.z;
    const ushort* Ab = A + (long long)bz * sA;
    const ushort* Bb = BT + (long long)bz * sB;

    const int tm = blockIdx.y;
    const int tn = blockIdx.x;

    const int lane = tid & 63;
    const int wave = tid >> 6;
    const int wm = (wave >> 1) * 64;
    const int wn = (wave & 1) * 64;
    const int quad = lane >> 4;
    const int l16 = lane & 15;

    // staging: thread t covers row (t>>1), 16-element segment (t&1)
    const int srow = tid >> 1;
    const int sseg = (tid & 1) * 16;
    const ushort* Ag = Ab + (long long)(tm * BM + srow) * K + sseg;
    const ushort* Bg = Bb + (long long)(tn * BN + srow) * K + sseg;
    ushort* Asw = &As[srow * LDSP + sseg];
    ushort* Bsw = &Bs[srow * LDSP + sseg];

    f32x4 acc[4][4];
#pragma unroll
    for (int i = 0; i < 4; i++)
#pragma unroll
        for (int j = 0; j < 4; j++) acc[i][j] = (f32x4){0.f, 0.f, 0.f, 0.f};

    for (int k0 = 0; k0 < K; k0 += BKK) {
        uint4 a0 = *(const uint4*)(Ag + k0);
        uint4 a1 = *(const uint4*)(Ag + k0 + 8);
        uint4 b0 = *(const uint4*)(Bg + k0);
        uint4 b1 = *(const uint4*)(Bg + k0 + 8);
        *(uint4*)(Asw) = a0;
        *(uint4*)(Asw + 8) = a1;
        *(uint4*)(Bsw) = b0;
        *(uint4*)(Bsw + 8) = b1;
        __syncthreads();

        s16x8 af[4], bf[4];
#pragma unroll
        for (int i = 0; i < 4; i++)
            af[i] = *(const s16x8*)&As[(wm + i * 16 + l16) * LDSP + quad * 8];
#pragma unroll
        for (int j = 0; j < 4; j++)
            bf[j] = *(const s16x8*)&Bs[(wn + j * 16 + l16) * LDSP + quad * 8];
#pragma unroll
        for (int i = 0; i < 4; i++)
#pragma unroll
            for (int j = 0; j < 4; j++)
                acc[i][j] = __builtin_amdgcn_mfma_f32_16x16x32_bf16(af[i], bf[j], acc[i][j], 0, 0, 0);
        __syncthreads();
    }

    // epilogue: C/D layout col = lane&15, row = quad*4 + reg  [verified m89/m91]
    const long long cb = (long long)bz * sC;
    float* Cf = (float*)Cp;
    ushort* Cb = (ushort*)Cp;
#pragma unroll
    for (int j = 0; j < 4; j++) {
        const int col = tn * BN + wn + j * 16 + l16;
        float bv = HAS_BIAS ? bias[col] : 0.0f;
#pragma unroll
        for (int i = 0; i < 4; i++) {
            const int row0 = tm * BM + wm + i * 16 + quad * 4;
#pragma unroll
            for (int r = 0; r < 4; r++) {
                float v = acc[i][j][r] * scale + bv;
                if (RELU) v = v > 0.f ? v : 0.f;
                long long idx = cb + (long long)(row0 + r) * N + col;
                if (OUT_BF16) Cb[idx] = f2b(v);
                else Cf[idx] = v;
            }
        }
    }
}

// ---------------- row softmax: fp32 [rows][2048] -> bf16 ----------------

__global__ __launch_bounds__(256) void softmax_rows(const float* __restrict__ S,
                                                    ushort* __restrict__ P) {
    const int C = 2048;
    const long long row = blockIdx.x;
    const float* s = S + row * C;
    ushort* p = P + row * C;
    const int tid = threadIdx.x;
    float v[8];
    float mx = -1e30f;
#pragma unroll
    for (int i = 0; i < 8; i++) {
        v[i] = s[tid + i * 256];
        mx = fmaxf(mx, v[i]);
    }
    __shared__ float red[256];
    red[tid] = mx;
    __syncthreads();
    for (int off = 128; off > 0; off >>= 1) {
        if (tid < off) red[tid] = fmaxf(red[tid], red[tid + off]);
        __syncthreads();
    }
    mx = red[0];
    __syncthreads();
    float sum = 0.f;
#pragma unroll
    for (int i = 0; i < 8; i++) {
        v[i] = __expf(v[i] - mx);
        sum += v[i];
    }
    red[tid] = sum;
    __syncthreads();
    for (int off = 128; off > 0; off >>= 1) {
        if (tid < off) red[tid] += red[tid + off];
        __syncthreads();
    }
    float inv = 1.f / red[0];
#pragma unroll
    for (int i = 0; i < 8; i++) p[tid + i * 256] = f2b(v[i] * inv);
}

// ---------------- fused residual + LayerNorm (D=1024), fp32 out + optional bf16 out ----

__global__ __launch_bounds__(256) void residual_ln(const float* __restrict__ X,
                                                   const float* __restrict__ Y,
                                                   const float* __restrict__ g,
                                                   const float* __restrict__ be,
                                                   float* __restrict__ outf,
                                                   ushort* __restrict__ outb) {
    const int D = 1024;
    const long long row = blockIdx.x;
    const float* x = X + row * D;
    const float* y = Y + row * D;
    const int tid = threadIdx.x;
    float v[4];
    float s = 0.f, s2 = 0.f;
#pragma unroll
    for (int i = 0; i < 4; i++) {
        int c = tid + i * 256;
        float t = x[c] + y[c];
        v[i] = t;
        s += t;
        s2 += t * t;
    }
    __shared__ float r1[256], r2[256];
    r1[tid] = s;
    r2[tid] = s2;
    __syncthreads();
    for (int off = 128; off > 0; off >>= 1) {
        if (tid < off) {
            r1[tid] += r1[tid + off];
            r2[tid] += r2[tid + off];
        }
        __syncthreads();
    }
    float mu = r1[0] * (1.f / 1024.f);
    float var = r2[0] * (1.f / 1024.f) - mu * mu;
    float inv = rsqrtf(var + 1e-5f);
    float* of = outf + row * D;
    ushort* ob = outb ? outb + row * D : nullptr;
#pragma unroll
    for (int i = 0; i < 4; i++) {
        int c = tid + i * 256;
        float o = (v[i] - mu) * inv * g[c] + be[c];
        of[c] = o;
        if (ob) ob[c] = f2b(o);
    }
}

// ---------------- launch ----------------

extern "C" void kernel_launch(void* const* d_in, const int* in_sizes, int n_in,
                              void* d_out, int out_size, void* d_ws, size_t ws_size,
                              hipStream_t stream) {
    const float* x  = (const float*)d_in[0];
    const float* wq = (const float*)d_in[1];
    const float* bq = (const float*)d_in[2];
    const float* wk = (const float*)d_in[3];
    const float* bk = (const float*)d_in[4];
    const float* wv = (const float*)d_in[5];
    const float* bv = (const float*)d_in[6];
    const float* wo = (const float*)d_in[7];
    const float* bo = (const float*)d_in[8];
    const float* w1 = (const float*)d_in[9];
    const float* b1 = (const float*)d_in[10];
    const float* w2 = (const float*)d_in[11];
    const float* b2 = (const float*)d_in[12];
    const float* g1 = (const float*)d_in[13];
    const float* be1 = (const float*)d_in[14];
    const float* g2 = (const float*)d_in[15];
    const float* be2 = (const float*)d_in[16];
    float* out = (float*)d_out;
    char* ws = (char*)d_ws;

    const int Bz = 4, S = 2048, D = 1024, F = 4096;
    const int T = Bz * S;  // 8192 rows
    const size_t MBy = 1024ull * 1024ull;

    // workspace layout (byte offsets), with lifetime-based reuse; peak 200 MB
    ushort* xb  = (ushort*)(ws + 0);        // 16 MB  bf16 x
    ushort* wqT = (ushort*)(ws + 16 * MBy); // 2 MB
    ushort* wkT = (ushort*)(ws + 18 * MBy);
    ushort* wvT = (ushort*)(ws + 20 * MBy);
    ushort* woT = (ushort*)(ws + 22 * MBy);
    ushort* w1T = (ushort*)(ws + 24 * MBy); // 8 MB  [F][D]
    ushort* w2T = (ushort*)(ws + 32 * MBy); // 8 MB  [D][F]
    ushort* qb  = (ushort*)(ws + 40 * MBy); // 16 MB
    ushort* kb  = (ushort*)(ws + 56 * MBy); // 16 MB
    ushort* vb  = (ushort*)(ws + 72 * MBy); // 16 MB
    ushort* vT  = (ushort*)(ws + 88 * MBy); // 16 MB  [B][D][S]
    float*  sc  = (float*)(ws + 104 * MBy); // 64 MB  scores fp32
    ushort* attn = (ushort*)(ws + 168 * MBy); // 32 MB
    // reuse (non-overlapping lifetimes):
    ushort* ctx = (ushort*)(ws + 40 * MBy);  // over qb (dead after scores)
    float*  ao  = (float*)(ws + 104 * MBy);  // over sc (dead after softmax)
    float*  x1  = (float*)(ws + 56 * MBy);   // over kb+vb (32 MB)
    ushort* x1b = (ushort*)(ws + 88 * MBy);  // over vT (dead after ctx)
    ushort* h   = (ushort*)(ws + 104 * MBy); // over sc/ao (ao dead after ln1)
    float*  ff  = (float*)(ws + 168 * MBy);  // over attn (dead after ctx)

    dim3 b32(32, 8);

    // 1) cast x -> bf16
    cast_f2b4<<<(T * D) / 1024, 256, 0, stream>>>(x, xb, (long long)(T * D) / 4);

    // 2) transpose-cast weights to [N][K] bf16
    transpose_to_bf16<float><<<dim3(32, 32, 1), b32, 0, stream>>>(wq, wqT, D, D, 0, 0);
    transpose_to_bf16<float><<<dim3(32, 32, 1), b32, 0, stream>>>(wk, wkT, D, D, 0, 0);
    transpose_to_bf16<float><<<dim3(32, 32, 1), b32, 0, stream>>>(wv, wvT, D, D, 0, 0);
    transpose_to_bf16<float><<<dim3(32, 32, 1), b32, 0, stream>>>(wo, woT, D, D, 0, 0);
    transpose_to_bf16<float><<<dim3(128, 32, 1), b32, 0, stream>>>(w1, w1T, D, F, 0, 0);
    transpose_to_bf16<float><<<dim3(32, 128, 1), b32, 0, stream>>>(w2, w2T, F, D, 0, 0);

    // 3) QKV projections (bf16 out, +bias)
    gemm_bt<1, 0, 1><<<dim3(D / 128, T / 128, 1), 256, 0, stream>>>(xb, wqT, qb, bq, T, D, D, 1.f, 0, 0, 0);
    gemm_bt<1, 0, 1><<<dim3(D / 128, T / 128, 1), 256, 0, stream>>>(xb, wkT, kb, bk, T, D, D, 1.f, 0, 0, 0);
    gemm_bt<1, 0, 1><<<dim3(D / 128, T / 128, 1), 256, 0, stream>>>(xb, wvT, vb, bv, T, D, D, 1.f, 0, 0, 0);

    // 4) V^T per batch: [S][D] -> [D][S]
    transpose_to_bf16<ushort><<<dim3(D / 32, S / 32, Bz), b32, 0, stream>>>(
        vb, vT, S, D, (long long)S * D, (long long)S * D);

    // 5) scores = Q K^T / 32 (fp32 out); K already in BT=[N=S][K=D] layout
    gemm_bt<0, 0, 0><<<dim3(S / 128, S / 128, Bz), 256, 0, stream>>>(
        qb, kb, sc, nullptr, S, S, D, 0.03125f,
        (long long)S * D, (long long)S * D, (long long)S * S);

    // 6) softmax rows -> bf16 attn
    softmax_rows<<<T, 256, 0, stream>>>(sc, attn);

    // 7) ctx = attn @ V  (BT = V^T [D][S])
    gemm_bt<1, 0, 0><<<dim3(D / 128, S / 128, Bz), 256, 0, stream>>>(
        attn, vT, ctx, nullptr, S, D, S, 1.f,
        (long long)S * S, (long long)D * S, (long long)S * D);

    // 8) attn_out = ctx @ wo^T + bo (fp32 out)
    gemm_bt<0, 0, 1><<<dim3(D / 128, T / 128, 1), 256, 0, stream>>>(ctx, woT, ao, bo, T, D, D, 1.f, 0, 0, 0);

    // 9) x1 = LN(x + ao) -> fp32 + bf16
    residual_ln<<<T, 256, 0, stream>>>(x, ao, g1, be1, x1, x1b);

    // 10) h = relu(x1 @ w1 + b1) (bf16)
    gemm_bt<1, 1, 1><<<dim3(F / 128, T / 128, 1), 256, 0, stream>>>(x1b, w1T, h, b1, T, F, D, 1.f, 0, 0, 0);

    // 11) ff = h @ w2 + b2 (fp32)
    gemm_bt<0, 0, 1><<<dim3(D / 128, T / 128, 1), 256, 0, stream>>>(h, w2T, ff, b2, T, D, F, 1.f, 0, 0, 0);

    // 12) out = LN(x1 + ff) -> d_out fp32
    residual_ln<<<T, 256, 0, stream>>>(x1, ff, g2, be2, out, nullptr);
}

// Round 2
// 670.332 us; speedup vs baseline: 1.0457x; 1.0457x over previous
//
#include <hip/hip_runtime.h>
#include <stdint.h>

// ---------------- common helpers ----------------

using f32x4 = __attribute__((ext_vector_type(4))) float;
using s16x8 = __attribute__((ext_vector_type(8))) short;

__device__ __forceinline__ ushort f2b(float f) {
    union { float f; uint32_t u; } v; v.f = f;
    uint32_t u = v.u;
    return (ushort)((u + 0x7fffu + ((u >> 16) & 1u)) >> 16);
}
__device__ __forceinline__ float b2f(ushort b) {
    union { uint32_t u; float f; } v; v.u = ((uint32_t)b) << 16;
    return v.f;
}
__device__ __forceinline__ float to_f(float f) { return f; }
__device__ __forceinline__ float to_f(ushort b) { return b2f(b); }

// async global->LDS, 16B per lane; LDS dest = wave-uniform base + lane*16
__device__ __forceinline__ void async_ld16(const ushort* g, ushort* l) {
    __builtin_amdgcn_global_load_lds(
        (const __attribute__((address_space(1))) void*)g,
        (__attribute__((address_space(3))) void*)l,
        16, 0, 0);
}

// ---------------- cast fp32 -> bf16 (vectorized x4) ----------------

__global__ __launch_bounds__(256) void cast_f2b4(const float* __restrict__ src,
                                                 ushort* __restrict__ dst,
                                                 long long n4) {
    long long i = (long long)blockIdx.x * 256 + threadIdx.x;
    if (i >= n4) return;
    float4 f = ((const float4*)src)[i];
    ushort4 o;
    o.x = f2b(f.x); o.y = f2b(f.y); o.z = f2b(f.z); o.w = f2b(f.w);
    ((ushort4*)dst)[i] = o;
}

// ---------------- transpose (fp32 or bf16 in) -> bf16 out ----------------
// src: [R][C] row-major, dst: [C][R] row-major. Grid: (C/32, R/32, batch), block (32,8).

template <typename T>
__global__ __launch_bounds__(256) void transpose_to_bf16(const T* __restrict__ src,
                                                         ushort* __restrict__ dst,
                                                         int R, int C,
                                                         long long ss, long long ds) {
    __shared__ float tile[32][33];
    src += (long long)blockIdx.z * ss;
    dst += (long long)blockIdx.z * ds;
    const int c0 = blockIdx.x * 32;
    const int r0 = blockIdx.y * 32;
    const int tx = threadIdx.x, ty = threadIdx.y;
#pragma unroll
    for (int i = 0; i < 4; i++) {
        int r = r0 + ty + i * 8;
        tile[ty + i * 8][tx] = to_f(src[(long long)r * C + c0 + tx]);
    }
    __syncthreads();
#pragma unroll
    for (int i = 0; i < 4; i++) {
        int r = c0 + ty + i * 8;  // row of dst, in [0, C)
        dst[(long long)r * R + r0 + tx] = f2b(tile[tx][ty + i * 8]);
    }
}

// ---------------- bf16 MFMA GEMM:  C[M,N] = A[M,K] * BT[N,K]^T (+bias, relu, scale) ----
// 128x128 tile per 256-thread block (4 waves, each 64x64 = 4x4 MFMA 16x16x32 tiles).
// Staging via global_load_lds width=16 (m97 structure): UNPADDED LDS [row][32],
// wave w instr i covers rows w*32+i*16..+16; lane l -> row +(l>>2), col (l&3)*8.
// Grid: (N/128, M/128, batch). All dims must divide exactly (true for all uses here).

#define BM 128
#define BN 128
#define BKK 32

template <int OUT_BF16, int RELU, int HAS_BIAS>
__global__ __launch_bounds__(256) void gemm_bt(const ushort* __restrict__ A,
                                               const ushort* __restrict__ BT,
                                               void* __restrict__ Cp,
                                               const float* __restrict__ bias,
                                               int M, int N, int K, float scale,
                                               long long sA, long long sB, long long sC) {
    __shared__ ushort As[BM * BKK];
    __shared__ ushort Bs[BN * BKK];

    const int tid = threadIdx.x;
    const int bz = blockIdx.z;
    const ushort* Ab = A + (long long)bz * sA;
    const ushort* Bb = BT + (long long)bz * sB;

    const int tm = blockIdx.y;
    const int tn = blockIdx.x;

    const int lane = tid & 63;
    const int wave = tid >> 6;
    const int wm = (wave >> 1) * 64;
    const int wn = (wave & 1) * 64;
    const int quad = lane >> 4;
    const int l16 = lane & 15;

    // async staging addresses: wave covers rows [wave*32, wave*32+32)
    const int srow = wave * 32 + (lane >> 2);  // instr 1 adds 16 rows
    const int scol = (lane & 3) * 8;
    const ushort* AgL = Ab + (long long)(tm * BM + srow) * K + scol;
    const ushort* BgL = Bb + (long long)(tn * BN + srow) * K + scol;
    ushort* AsL = As + wave * 1024;  // wave*2048 bytes; instr 1 adds 512 elems
    ushort* BsL = Bs + wave * 1024;
    const long long rstep = (long long)16 * K;

    f32x4 acc[4][4];
#pragma unroll
    for (int i = 0; i < 4; i++)
#pragma unroll
        for (int j = 0; j < 4; j++) acc[i][j] = (f32x4){0.f, 0.f, 0.f, 0.f};

    for (int k0 = 0; k0 < K; k0 += BKK) {
        async_ld16(AgL + k0, AsL);
        async_ld16(AgL + rstep + k0, AsL + 512);
        async_ld16(BgL + k0, BsL);
        async_ld16(BgL + rstep + k0, BsL + 512);
        __syncthreads();  // compiler emits s_waitcnt vmcnt(0) before s_barrier

        s16x8 af[4], bf[4];
#pragma unroll
        for (int i = 0; i < 4; i++)
            af[i] = *(const s16x8*)&As[(wm + i * 16 + l16) * BKK + quad * 8];
#pragma unroll
        for (int j = 0; j < 4; j++)
            bf[j] = *(const s16x8*)&Bs[(wn + j * 16 + l16) * BKK + quad * 8];
#pragma unroll
        for (int i = 0; i < 4; i++)
#pragma unroll
            for (int j = 0; j < 4; j++)
                acc[i][j] = __builtin_amdgcn_mfma_f32_16x16x32_bf16(af[i], bf[j], acc[i][j], 0, 0, 0);
        __syncthreads();
    }

    // epilogue: C/D layout col = lane&15, row = quad*4 + reg  [verified m89/m91]
    const long long cb = (long long)bz * sC;
    float* Cf = (float*)Cp;
    ushort* Cb = (ushort*)Cp;
#pragma unroll
    for (int j = 0; j < 4; j++) {
        const int col = tn * BN + wn + j * 16 + l16;
        float bv = HAS_BIAS ? bias[col] : 0.0f;
#pragma unroll
        for (int i = 0; i < 4; i++) {
            const int row0 = tm * BM + wm + i * 16 + quad * 4;
#pragma unroll
            for (int r = 0; r < 4; r++) {
                float v = acc[i][j][r] * scale + bv;
                if (RELU) v = v > 0.f ? v : 0.f;
                long long idx = cb + (long long)(row0 + r) * N + col;
                if (OUT_BF16) Cb[idx] = f2b(v);
                else Cf[idx] = v;
            }
        }
    }
}

// ---------------- row softmax: fp32 [rows][2048] -> bf16 ----------------

__global__ __launch_bounds__(256) void softmax_rows(const float* __restrict__ S,
                                                    ushort* __restrict__ P) {
    const int C = 2048;
    const long long row = blockIdx.x;
    const float* s = S + row * C;
    ushort* p = P + row * C;
    const int tid = threadIdx.x;
    float v[8];
    float mx = -1e30f;
#pragma unroll
    for (int i = 0; i < 8; i++) {
        v[i] = s[tid + i * 256];
        mx = fmaxf(mx, v[i]);
    }
    __shared__ float red[256];
    red[tid] = mx;
    __syncthreads();
    for (int off = 128; off > 0; off >>= 1) {
        if (tid < off) red[tid] = fmaxf(red[tid], red[tid + off]);
        __syncthreads();
    }
    mx = red[0];
    __syncthreads();
    float sum = 0.f;
#pragma unroll
    for (int i = 0; i < 8; i++) {
        v[i] = __expf(v[i] - mx);
        sum += v[i];
    }
    red[tid] = sum;
    __syncthreads();
    for (int off = 128; off > 0; off >>= 1) {
        if (tid < off) red[tid] += red[tid + off];
        __syncthreads();
    }
    float inv = 1.f / red[0];
#pragma unroll
    for (int i = 0; i < 8; i++) p[tid + i * 256] = f2b(v[i] * inv);
}

// ---------------- fused residual + LayerNorm (D=1024), fp32 out + optional bf16 out ----

__global__ __launch_bounds__(256) void residual_ln(const float* __restrict__ X,
                                                   const float* __restrict__ Y,
                                                   const float* __restrict__ g,
                                                   const float* __restrict__ be,
                                                   float* __restrict__ outf,
                                                   ushort* __restrict__ outb) {
    const int D = 1024;
    const long long row = blockIdx.x;
    const float* x = X + row * D;
    const float* y = Y + row * D;
    const int tid = threadIdx.x;
    float v[4];
    float s = 0.f, s2 = 0.f;
#pragma unroll
    for (int i = 0; i < 4; i++) {
        int c = tid + i * 256;
        float t = x[c] + y[c];
        v[i] = t;
        s += t;
        s2 += t * t;
    }
    __shared__ float r1[256], r2[256];
    r1[tid] = s;
    r2[tid] = s2;
    __syncthreads();
    for (int off = 128; off > 0; off >>= 1) {
        if (tid < off) {
            r1[tid] += r1[tid + off];
            r2[tid] += r2[tid + off];
        }
        __syncthreads();
    }
    float mu = r1[0] * (1.f / 1024.f);
    float var = r2[0] * (1.f / 1024.f) - mu * mu;
    float inv = rsqrtf(var + 1e-5f);
    float* of = outf + row * D;
    ushort* ob = outb ? outb + row * D : nullptr;
#pragma unroll
    for (int i = 0; i < 4; i++) {
        int c = tid + i * 256;
        float o = (v[i] - mu) * inv * g[c] + be[c];
        of[c] = o;
        if (ob) ob[c] = f2b(o);
    }
}

// ---------------- launch ----------------

extern "C" void kernel_launch(void* const* d_in, const int* in_sizes, int n_in,
                              void* d_out, int out_size, void* d_ws, size_t ws_size,
                              hipStream_t stream) {
    const float* x  = (const float*)d_in[0];
    const float* wq = (const float*)d_in[1];
    const float* bq = (const float*)d_in[2];
    const float* wk = (const float*)d_in[3];
    const float* bk = (const float*)d_in[4];
    const float* wv = (const float*)d_in[5];
    const float* bv = (const float*)d_in[6];
    const float* wo = (const float*)d_in[7];
    const float* bo = (const float*)d_in[8];
    const float* w1 = (const float*)d_in[9];
    const float* b1 = (const float*)d_in[10];
    const float* w2 = (const float*)d_in[11];
    const float* b2 = (const float*)d_in[12];
    const float* g1 = (const float*)d_in[13];
    const float* be1 = (const float*)d_in[14];
    const float* g2 = (const float*)d_in[15];
    const float* be2 = (const float*)d_in[16];
    float* out = (float*)d_out;
    char* ws = (char*)d_ws;

    const int Bz = 4, S = 2048, D = 1024, F = 4096;
    const int T = Bz * S;  // 8192 rows
    const size_t MBy = 1024ull * 1024ull;

    // workspace layout (byte offsets), with lifetime-based reuse; peak 200 MB
    ushort* xb  = (ushort*)(ws + 0);        // 16 MB  bf16 x
    ushort* wqT = (ushort*)(ws + 16 * MBy); // 2 MB
    ushort* wkT = (ushort*)(ws + 18 * MBy);
    ushort* wvT = (ushort*)(ws + 20 * MBy);
    ushort* woT = (ushort*)(ws + 22 * MBy);
    ushort* w1T = (ushort*)(ws + 24 * MBy); // 8 MB  [F][D]
    ushort* w2T = (ushort*)(ws + 32 * MBy); // 8 MB  [D][F]
    ushort* qb  = (ushort*)(ws + 40 * MBy); // 16 MB
    ushort* kb  = (ushort*)(ws + 56 * MBy); // 16 MB
    ushort* vb  = (ushort*)(ws + 72 * MBy); // 16 MB
    ushort* vT  = (ushort*)(ws + 88 * MBy); // 16 MB  [B][D][S]
    float*  sc  = (float*)(ws + 104 * MBy); // 64 MB  scores fp32
    ushort* attn = (ushort*)(ws + 168 * MBy); // 32 MB
    // reuse (non-overlapping lifetimes):
    ushort* ctx = (ushort*)(ws + 40 * MBy);  // over qb (dead after scores)
    float*  ao  = (float*)(ws + 104 * MBy);  // over sc (dead after softmax)
    float*  x1  = (float*)(ws + 56 * MBy);   // over kb+vb (32 MB)
    ushort* x1b = (ushort*)(ws + 88 * MBy);  // over vT (dead after ctx)
    ushort* h   = (ushort*)(ws + 104 * MBy); // over sc/ao (ao dead after ln1)
    float*  ff  = (float*)(ws + 168 * MBy);  // over attn (dead after ctx)

    dim3 b32(32, 8);

    // 1) cast x -> bf16
    cast_f2b4<<<(T * D) / 1024, 256, 0, stream>>>(x, xb, (long long)(T * D) / 4);

    // 2) transpose-cast weights to [N][K] bf16
    transpose_to_bf16<float><<<dim3(32, 32, 1), b32, 0, stream>>>(wq, wqT, D, D, 0, 0);
    transpose_to_bf16<float><<<dim3(32, 32, 1), b32, 0, stream>>>(wk, wkT, D, D, 0, 0);
    transpose_to_bf16<float><<<dim3(32, 32, 1), b32, 0, stream>>>(wv, wvT, D, D, 0, 0);
    transpose_to_bf16<float><<<dim3(32, 32, 1), b32, 0, stream>>>(wo, woT, D, D, 0, 0);
    transpose_to_bf16<float><<<dim3(128, 32, 1), b32, 0, stream>>>(w1, w1T, D, F, 0, 0);
    transpose_to_bf16<float><<<dim3(32, 128, 1), b32, 0, stream>>>(w2, w2T, F, D, 0, 0);

    // 3) QKV projections (bf16 out, +bias)
    gemm_bt<1, 0, 1><<<dim3(D / 128, T / 128, 1), 256, 0, stream>>>(xb, wqT, qb, bq, T, D, D, 1.f, 0, 0, 0);
    gemm_bt<1, 0, 1><<<dim3(D / 128, T / 128, 1), 256, 0, stream>>>(xb, wkT, kb, bk, T, D, D, 1.f, 0, 0, 0);
    gemm_bt<1, 0, 1><<<dim3(D / 128, T / 128, 1), 256, 0, stream>>>(xb, wvT, vb, bv, T, D, D, 1.f, 0, 0, 0);

    // 4) V^T per batch: [S][D] -> [D][S]
    transpose_to_bf16<ushort><<<dim3(D / 32, S / 32, Bz), b32, 0, stream>>>(
        vb, vT, S, D, (long long)S * D, (long long)S * D);

    // 5) scores = Q K^T / 32 (fp32 out); K already in BT=[N=S][K=D] layout
    gemm_bt<0, 0, 0><<<dim3(S / 128, S / 128, Bz), 256, 0, stream>>>(
        qb, kb, sc, nullptr, S, S, D, 0.03125f,
        (long long)S * D, (long long)S * D, (long long)S * S);

    // 6) softmax rows -> bf16 attn
    softmax_rows<<<T, 256, 0, stream>>>(sc, attn);

    // 7) ctx = attn @ V  (BT = V^T [D][S])
    gemm_bt<1, 0, 0><<<dim3(D / 128, S / 128, Bz), 256, 0, stream>>>(
        attn, vT, ctx, nullptr, S, D, S, 1.f,
        (long long)S * S, (long long)D * S, (long long)S * D);

    // 8) attn_out = ctx @ wo^T + bo (fp32 out)
    gemm_bt<0, 0, 1><<<dim3(D / 128, T / 128, 1), 256, 0, stream>>>(ctx, woT, ao, bo, T, D, D, 1.f, 0, 0, 0);

    // 9) x1 = LN(x + ao) -> fp32 + bf16
    residual_ln<<<T, 256, 0, stream>>>(x, ao, g1, be1, x1, x1b);

    // 10) h = relu(x1 @ w1 + b1) (bf16)
    gemm_bt<1, 1, 1><<<dim3(F / 128, T / 128, 1), 256, 0, stream>>>(x1b, w1T, h, b1, T, F, D, 1.f, 0, 0, 0);

    // 11) ff = h @ w2 + b2 (fp32)
    gemm_bt<0, 0, 1><<<dim3(D / 128, T / 128, 1), 256, 0, stream>>>(h, w2T, ff, b2, T, D, F, 1.f, 0, 0, 0);

    // 12) out = LN(x1 + ff) -> d_out fp32
    residual_ln<<<T, 256, 0, stream>>>(x1, ff, g2, be2, out, nullptr);
}